// Round 20
// baseline (68.453 us; speedup 1.0000x reference)
//
#include <hip/hip_runtime.h>

// Conv1dFFT via polyphase: y[b] = IFFT_8192( sum_p G_p * FFT_8192(x_polyphase_p) )
// R19 structure (acc in LDS, x read once, C0-keep, P-hoist) + Q-table loads
// hoisted after C6 so their latency hides under C3+C0 instead of stalling
// the accumulate phase (symmetric completion of the R19 P-hoist).

#define TK      8192
#define LOG2TK  13
#define HALF_TK 4096
#define KFOLD   8
#define NPAIR   4
#define TFULL   65536
#define NT      1024
#define RSQ2    0.70710678118654752440f

// LDS bank-conflict swizzle (bijective: low 4 bits XOR bits 4..7)
#define SW(i) ((i) ^ (((i) >> 4) & 15))

// Compiler-only ordering fence for wave-synchronous LDS hand-offs.
#define WAVE_SYNC() do { asm volatile("" ::: "memory"); __builtin_amdgcn_wave_barrier(); } while (0)
#define SCHED_FENCE() __builtin_amdgcn_sched_barrier(0)

__device__ __forceinline__ float2 cmul(float2 a, float2 b) {
    return make_float2(a.x * b.x - a.y * b.y, a.x * b.y + a.y * b.x);
}
__device__ __forceinline__ unsigned br13(unsigned r) { return __brev(r) >> 19u; }

__device__ float2 g_W[HALF_TK];        // e^{-2pi i t/8192}
__device__ float2 g_P[NPAIR * TK];     // bit-reversed order
__device__ float2 g_Q[NPAIR * TK];     // bit-reversed order

// Merged build (R15-validated): g_W (t<4096) + P/Q (all t).
__global__ void build_tables_kernel(const float* __restrict__ filt) {
    int t = blockIdx.x * blockDim.x + threadIdx.x;
    if (t >= TK) return;
    if (t < HALF_TK) {
        float ang = -6.28318530717958647693f * (float)t / (float)TK;
        float c, s;
        __sincosf(ang, &s, &c);
        g_W[t] = make_float2(c, s);
    }
    const float c8[8] = { 1.f,  RSQ2,  0.f, -RSQ2, -1.f, -RSQ2,  0.f,  RSQ2 };
    const float s8[8] = { 0.f, -RSQ2, -1.f, -RSQ2,  0.f,  RSQ2,  1.f,  RSQ2 };
    float fm[KFOLD];
#pragma unroll
    for (int m = 0; m < KFOLD; ++m) fm[m] = filt[m * TK + t];
    float2 G[KFOLD];
#pragma unroll
    for (int p = 0; p < KFOLD; ++p) {
        float sr = 0.f, si = 0.f;
#pragma unroll
        for (int m = 0; m < KFOLD; ++m) {
            int k = (p * m) & 7;
            sr += fm[m] * c8[k];
            si += fm[m] * s8[k];
        }
        float ang2 = -6.28318530717958647693f * (float)(p * t) / (float)TFULL;
        float c2, s2;
        __sincosf(ang2, &s2, &c2);
        G[p] = make_float2((sr * c2 - si * s2) * 0.125f,
                           (sr * s2 + si * c2) * 0.125f);
    }
    const float norm = 0.5f / (float)TK;
    unsigned r = br13((unsigned)t);
#pragma unroll
    for (int j = 0; j < NPAIR; ++j) {
        float2 g0 = G[2 * j], g1 = G[2 * j + 1];
        g_P[j * TK + r] = make_float2((g0.x + g1.y) * norm, (g0.y - g1.x) * norm);
        g_Q[j * TK + r] = make_float2((g0.x - g1.y) * norm, (g0.y + g1.x) * norm);
    }
}

// Forward DIF radix-8 pass: stages (4s, 2s, s), s = 1<<C.
template<int C>
__device__ __forceinline__ void fwd_pass(float2* buf, int tid) {
    const int s = 1 << C;
    const int q0 = tid & (s - 1);
    const int i0 = ((tid >> C) << (C + 3)) + q0;
    float2 e[8];
#pragma unroll
    for (int t = 0; t < 8; ++t) e[t] = buf[SW(i0 + t * s)];
    float2 w1 = g_W[q0 << (10 - C)];
    float2 w2 = cmul(w1, w1), w3 = cmul(w2, w2);
#pragma unroll
    for (int t = 0; t < 4; ++t) {
        float2 a = e[t], b = e[t + 4];
        float2 d = make_float2(a.x - b.x, a.y - b.y);
        e[t] = make_float2(a.x + b.x, a.y + b.y);
        d = cmul(d, w1);
        if (t == 1)      d = make_float2(RSQ2 * (d.x + d.y), RSQ2 * (d.y - d.x));
        else if (t == 2) d = make_float2(d.y, -d.x);
        else if (t == 3) d = make_float2(RSQ2 * (d.y - d.x), -RSQ2 * (d.x + d.y));
        e[t + 4] = d;
    }
#pragma unroll
    for (int t0 = 0; t0 < 8; t0 += 4) {
#pragma unroll
        for (int t = 0; t < 2; ++t) {
            int i = t0 + t;
            float2 a = e[i], b = e[i + 2];
            float2 d = make_float2(a.x - b.x, a.y - b.y);
            e[i] = make_float2(a.x + b.x, a.y + b.y);
            d = cmul(d, w2);
            if (t == 1) d = make_float2(d.y, -d.x);
            e[i + 2] = d;
        }
    }
#pragma unroll
    for (int t = 0; t < 8; t += 2) {
        float2 a = e[t], b = e[t + 1];
        float2 d = make_float2(a.x - b.x, a.y - b.y);
        e[t] = make_float2(a.x + b.x, a.y + b.y);
        e[t + 1] = cmul(d, w3);
    }
#pragma unroll
    for (int t = 0; t < 8; ++t) buf[SW(i0 + t * s)] = e[t];
}

// C0 pass (unit twiddles) that KEEPS its outputs in e[] (Zt for the acc).
__device__ __forceinline__ void fwd_pass0_keep(float2* buf, int tid, float2* e) {
    const int i0 = tid << 3;
#pragma unroll
    for (int t = 0; t < 8; ++t) e[t] = buf[SW(i0 + t)];
#pragma unroll
    for (int t = 0; t < 4; ++t) {
        float2 a = e[t], b = e[t + 4];
        float2 d = make_float2(a.x - b.x, a.y - b.y);
        e[t] = make_float2(a.x + b.x, a.y + b.y);
        if (t == 1)      d = make_float2(RSQ2 * (d.x + d.y), RSQ2 * (d.y - d.x));
        else if (t == 2) d = make_float2(d.y, -d.x);
        else if (t == 3) d = make_float2(RSQ2 * (d.y - d.x), -RSQ2 * (d.x + d.y));
        e[t + 4] = d;
    }
#pragma unroll
    for (int t0 = 0; t0 < 8; t0 += 4) {
#pragma unroll
        for (int t = 0; t < 2; ++t) {
            int i = t0 + t;
            float2 a = e[i], b = e[i + 2];
            float2 d = make_float2(a.x - b.x, a.y - b.y);
            e[i] = make_float2(a.x + b.x, a.y + b.y);
            if (t == 1) d = make_float2(d.y, -d.x);
            e[i + 2] = d;
        }
    }
#pragma unroll
    for (int t = 0; t < 8; t += 2) {
        float2 a = e[t], b = e[t + 1];
        e[t]     = make_float2(a.x + b.x, a.y + b.y);
        e[t + 1] = make_float2(a.x - b.x, a.y - b.y);
    }
#pragma unroll
    for (int t = 0; t < 8; ++t) buf[SW(i0 + t)] = e[t];
}

// Inverse DIT radix-8 pass: stages (s, 2s, 4s), conjugated twiddles.
template<int C>
__device__ __forceinline__ void inv_pass(float2* buf, int tid) {
    const int s = 1 << C;
    const int q0 = tid & (s - 1);
    const int i0 = ((tid >> C) << (C + 3)) + q0;
    float2 e[8];
#pragma unroll
    for (int t = 0; t < 8; ++t) e[t] = buf[SW(i0 + t * s)];
    float2 v1 = g_W[q0 << (10 - C)]; v1.y = -v1.y;
    float2 v2 = cmul(v1, v1), v3 = cmul(v2, v2);
#pragma unroll
    for (int t = 0; t < 8; t += 2) {
        float2 b = cmul(e[t + 1], v3);
        float2 a = e[t];
        e[t]     = make_float2(a.x + b.x, a.y + b.y);
        e[t + 1] = make_float2(a.x - b.x, a.y - b.y);
    }
#pragma unroll
    for (int t0 = 0; t0 < 8; t0 += 4) {
#pragma unroll
        for (int t = 0; t < 2; ++t) {
            int i = t0 + t;
            float2 b = cmul(e[i + 2], v2);
            if (t == 1) b = make_float2(-b.y, b.x);
            float2 a = e[i];
            e[i]     = make_float2(a.x + b.x, a.y + b.y);
            e[i + 2] = make_float2(a.x - b.x, a.y - b.y);
        }
    }
#pragma unroll
    for (int t = 0; t < 4; ++t) {
        float2 b = cmul(e[t + 4], v1);
        if (t == 1)      b = make_float2(RSQ2 * (b.x - b.y), RSQ2 * (b.x + b.y));
        else if (t == 2) b = make_float2(-b.y, b.x);
        else if (t == 3) b = make_float2(-RSQ2 * (b.x + b.y), RSQ2 * (b.x - b.y));
        float2 a = e[t];
        e[t]     = make_float2(a.x + b.x, a.y + b.y);
        e[t + 4] = make_float2(a.x - b.x, a.y - b.y);
    }
#pragma unroll
    for (int t = 0; t < 8; ++t) buf[SW(i0 + t * s)] = e[t];
}

__device__ __forceinline__ void stage1_store(float2* buf, int u, float2 a, float2 b2) {
    float2 w = g_W[u];
    buf[SW(u)] = make_float2(a.x + b2.x, a.y + b2.y);
    buf[SW(u + HALF_TK)] = cmul(make_float2(a.x - b2.x, a.y - b2.y), w);
}

// FFT body (C9..C0, wave-chained tail) + accumulate into LDS accL.
// P loads hoisted before C6; Q loads hoisted after C6 (hide under C3+C0).
template<bool FIRST>
__device__ __forceinline__ void fft_body_acc_lds(float2* buf, float2* accL, int tid,
                                                 const float2* __restrict__ P,
                                                 const float2* __restrict__ Q) {
    __syncthreads();
    fwd_pass<9>(buf, tid);
    __syncthreads();
    // --- hoisted P loads: latency hides under C6/C3/C0 ---
    float2 Pv[8];
#pragma unroll
    for (int c = 0; c < 8; ++c) Pv[c] = P[8 * tid + c];
    SCHED_FENCE();
    fwd_pass<6>(buf, tid);
    WAVE_SYNC();
    // --- hoisted Q loads: latency hides under C3/C0 ---
    float2 Qv[8];
#pragma unroll
    for (int c = 0; c < 8; ++c) Qv[c] = Q[8 * tid + c];
    SCHED_FENCE();
    fwd_pass<3>(buf, tid);
    WAVE_SYNC();
    float2 e0[8];
    fwd_pass0_keep(buf, tid, e0);   // Zt stays in regs; buf write feeds Zm
    __syncthreads();
    // accL[8*tid+c] is per-thread-exclusive -> RMW with no barrier.
#pragma unroll
    for (int c = 0; c < 8; ++c) {
        int r = 8 * tid + c;
        unsigned t = br13((unsigned)r);
        unsigned tm = (TK - t) & (TK - 1);
        int r2 = (int)br13(tm);
        float2 Zt = e0[c];
        float2 Zm = buf[SW(r2)];
        float2 a;
        if (FIRST) { a = make_float2(0.f, 0.f); }
        else       { a = accL[SW(r)]; }
        a.x += Zt.x * Pv[c].x - Zt.y * Pv[c].y + Zm.x * Qv[c].x + Zm.y * Qv[c].y;
        a.y += Zt.x * Pv[c].y + Zt.y * Pv[c].x + Zm.x * Qv[c].y - Zm.y * Qv[c].x;
        accL[SW(r)] = a;
    }
    __syncthreads();   // buf reads done before next j's load overwrites
}

__global__ __launch_bounds__(NT, 4)   // (1024,4): proven VGPR=64 allocator mode
void conv_fft_kernel(const float* __restrict__ x, float2* __restrict__ out) {
    __shared__ float2 buf[TK];     // 64 KB FFT workspace
    __shared__ float2 accL[TK];    // 64 KB accumulator (per-thread slots)
    const int tid = threadIdx.x;
    const int b = blockIdx.x;
    const float4* __restrict__ xrow4 =
        reinterpret_cast<const float4*>(x + (size_t)b * TFULL);

    // ---- j = 0: load even float4s, use .xy, stash .zw for j = 1 ----
    float2 s1a[4], s1b[4];
#pragma unroll
    for (int c4 = 0; c4 < 4; ++c4) {
        int u = c4 * NT + tid;
        float4 A = xrow4[2 * u];
        float4 B = xrow4[2 * (u + HALF_TK)];
        s1a[c4] = make_float2(A.z, A.w);
        s1b[c4] = make_float2(B.z, B.w);
        stage1_store(buf, u, make_float2(A.x, A.y), make_float2(B.x, B.y));
    }
    fft_body_acc_lds<true>(buf, accL, tid, g_P + 0 * TK, g_Q + 0 * TK);

    // ---- j = 1: stage-1 from register stash ----
#pragma unroll
    for (int c4 = 0; c4 < 4; ++c4) {
        int u = c4 * NT + tid;
        stage1_store(buf, u, s1a[c4], s1b[c4]);
    }
    fft_body_acc_lds<false>(buf, accL, tid, g_P + 1 * TK, g_Q + 1 * TK);

    // ---- j = 2: load odd float4s, use .xy, stash .zw for j = 3 ----
#pragma unroll
    for (int c4 = 0; c4 < 4; ++c4) {
        int u = c4 * NT + tid;
        float4 A = xrow4[2 * u + 1];
        float4 B = xrow4[2 * (u + HALF_TK) + 1];
        s1a[c4] = make_float2(A.z, A.w);
        s1b[c4] = make_float2(B.z, B.w);
        stage1_store(buf, u, make_float2(A.x, A.y), make_float2(B.x, B.y));
    }
    fft_body_acc_lds<false>(buf, accL, tid, g_P + 2 * TK, g_Q + 2 * TK);

    // ---- j = 3: stage-1 from register stash ----
#pragma unroll
    for (int c4 = 0; c4 < 4; ++c4) {
        int u = c4 * NT + tid;
        stage1_store(buf, u, s1a[c4], s1b[c4]);
    }
    fft_body_acc_lds<false>(buf, accL, tid, g_P + 3 * TK, g_Q + 3 * TK);

    // ---- inverse tail: read own acc slots, reg inverse C0, then C3..C9 ----
    {
        float2 acc[8], e[8];
#pragma unroll
        for (int c = 0; c < 8; ++c) acc[c] = accL[SW(8 * tid + c)];
        // stage h = 1
#pragma unroll
        for (int t = 0; t < 8; t += 2) {
            float2 a = acc[t], bb = acc[t + 1];
            e[t]     = make_float2(a.x + bb.x, a.y + bb.y);
            e[t + 1] = make_float2(a.x - bb.x, a.y - bb.y);
        }
        // stage h = 2 (twiddle (+i)^(t&1))
#pragma unroll
        for (int t0 = 0; t0 < 8; t0 += 4) {
            {
                float2 a = e[t0], bb = e[t0 + 2];
                e[t0]     = make_float2(a.x + bb.x, a.y + bb.y);
                e[t0 + 2] = make_float2(a.x - bb.x, a.y - bb.y);
            }
            {
                float2 a = e[t0 + 1], bb = e[t0 + 3];
                bb = make_float2(-bb.y, bb.x);
                e[t0 + 1] = make_float2(a.x + bb.x, a.y + bb.y);
                e[t0 + 3] = make_float2(a.x - bb.x, a.y - bb.y);
            }
        }
        // stage h = 4 (twiddle conj(u8)^t)
#pragma unroll
        for (int t = 0; t < 4; ++t) {
            float2 bb = e[t + 4];
            if (t == 1)      bb = make_float2(RSQ2 * (bb.x - bb.y), RSQ2 * (bb.x + bb.y));
            else if (t == 2) bb = make_float2(-bb.y, bb.x);
            else if (t == 3) bb = make_float2(-RSQ2 * (bb.x + bb.y), RSQ2 * (bb.x - bb.y));
            float2 a = e[t];
            e[t]     = make_float2(a.x + bb.x, a.y + bb.y);
            e[t + 4] = make_float2(a.x - bb.x, a.y - bb.y);
        }
#pragma unroll
        for (int t = 0; t < 8; ++t) buf[SW(8 * tid + t)] = e[t];
    }
    WAVE_SYNC();
    // C0 -> C3 -> C6 same-wave; barrier before the cross-wave C9
    inv_pass<3>(buf, tid);
    WAVE_SYNC();
    inv_pass<6>(buf, tid);
    __syncthreads();
    inv_pass<9>(buf, tid);
    __syncthreads();
    // final DIT stage (h = 4096) fused with global store
    float2* __restrict__ orow = out + (size_t)b * TK;
#pragma unroll
    for (int c4 = 0; c4 < 4; ++c4) {
        int u = c4 * NT + tid;
        float2 a = buf[SW(u)];
        float2 w = g_W[u]; w.y = -w.y;
        float2 bb = cmul(buf[SW(u + HALF_TK)], w);
        orow[u]           = make_float2(a.x + bb.x, a.y + bb.y);
        orow[u + HALF_TK] = make_float2(a.x - bb.x, a.y - bb.y);
    }
}

extern "C" void kernel_launch(void* const* d_in, const int* in_sizes, int n_in,
                              void* d_out, int out_size, void* d_ws, size_t ws_size,
                              hipStream_t stream) {
    const float* x    = (const float*)d_in[0];
    const float* filt = (const float*)d_in[1];
    const int T = in_sizes[1];          // 65536
    const int B = in_sizes[0] / T;      // 256 rows
    (void)n_in; (void)d_ws; (void)ws_size; (void)out_size; (void)T;

    build_tables_kernel<<<TK / 256, 256, 0, stream>>>(filt);
    conv_fft_kernel<<<B, NT, 0, stream>>>(x, (float2*)d_out);
}

// Round 21
// 63.674 us; speedup vs baseline: 1.0751x; 1.0751x over previous
//
#include <hip/hip_runtime.h>

// Conv1dFFT via polyphase: y[b] = IFFT_8192( sum_p G_p * FFT_8192(x_polyphase_p) )
// R19 configuration (measured best: 58.5us steady): acc in LDS (spill-free),
// x read once via register stash, C0-keep (Zt in regs), first-j write-only acc,
// P-table loads hoisted above the C6/C3/C0 wave-chain (latency hidden under
// ~2us of compute). Q stays at point-of-use: R20 measured that hoisting BOTH
// tables overflows the 64-VGPR budget and nets a loss.

#define TK      8192
#define LOG2TK  13
#define HALF_TK 4096
#define KFOLD   8
#define NPAIR   4
#define TFULL   65536
#define NT      1024
#define RSQ2    0.70710678118654752440f

// LDS bank-conflict swizzle (bijective: low 4 bits XOR bits 4..7)
#define SW(i) ((i) ^ (((i) >> 4) & 15))

// Compiler-only ordering fence for wave-synchronous LDS hand-offs.
#define WAVE_SYNC() do { asm volatile("" ::: "memory"); __builtin_amdgcn_wave_barrier(); } while (0)
#define SCHED_FENCE() __builtin_amdgcn_sched_barrier(0)

__device__ __forceinline__ float2 cmul(float2 a, float2 b) {
    return make_float2(a.x * b.x - a.y * b.y, a.x * b.y + a.y * b.x);
}
__device__ __forceinline__ unsigned br13(unsigned r) { return __brev(r) >> 19u; }

__device__ float2 g_W[HALF_TK];        // e^{-2pi i t/8192}
__device__ float2 g_P[NPAIR * TK];     // bit-reversed order
__device__ float2 g_Q[NPAIR * TK];     // bit-reversed order

// Merged build (R15-validated): g_W (t<4096) + P/Q (all t).
__global__ void build_tables_kernel(const float* __restrict__ filt) {
    int t = blockIdx.x * blockDim.x + threadIdx.x;
    if (t >= TK) return;
    if (t < HALF_TK) {
        float ang = -6.28318530717958647693f * (float)t / (float)TK;
        float c, s;
        __sincosf(ang, &s, &c);
        g_W[t] = make_float2(c, s);
    }
    const float c8[8] = { 1.f,  RSQ2,  0.f, -RSQ2, -1.f, -RSQ2,  0.f,  RSQ2 };
    const float s8[8] = { 0.f, -RSQ2, -1.f, -RSQ2,  0.f,  RSQ2,  1.f,  RSQ2 };
    float fm[KFOLD];
#pragma unroll
    for (int m = 0; m < KFOLD; ++m) fm[m] = filt[m * TK + t];
    float2 G[KFOLD];
#pragma unroll
    for (int p = 0; p < KFOLD; ++p) {
        float sr = 0.f, si = 0.f;
#pragma unroll
        for (int m = 0; m < KFOLD; ++m) {
            int k = (p * m) & 7;
            sr += fm[m] * c8[k];
            si += fm[m] * s8[k];
        }
        float ang2 = -6.28318530717958647693f * (float)(p * t) / (float)TFULL;
        float c2, s2;
        __sincosf(ang2, &s2, &c2);
        G[p] = make_float2((sr * c2 - si * s2) * 0.125f,
                           (sr * s2 + si * c2) * 0.125f);
    }
    const float norm = 0.5f / (float)TK;
    unsigned r = br13((unsigned)t);
#pragma unroll
    for (int j = 0; j < NPAIR; ++j) {
        float2 g0 = G[2 * j], g1 = G[2 * j + 1];
        g_P[j * TK + r] = make_float2((g0.x + g1.y) * norm, (g0.y - g1.x) * norm);
        g_Q[j * TK + r] = make_float2((g0.x - g1.y) * norm, (g0.y + g1.x) * norm);
    }
}

// Forward DIF radix-8 pass: stages (4s, 2s, s), s = 1<<C.
template<int C>
__device__ __forceinline__ void fwd_pass(float2* buf, int tid) {
    const int s = 1 << C;
    const int q0 = tid & (s - 1);
    const int i0 = ((tid >> C) << (C + 3)) + q0;
    float2 e[8];
#pragma unroll
    for (int t = 0; t < 8; ++t) e[t] = buf[SW(i0 + t * s)];
    float2 w1 = g_W[q0 << (10 - C)];
    float2 w2 = cmul(w1, w1), w3 = cmul(w2, w2);
#pragma unroll
    for (int t = 0; t < 4; ++t) {
        float2 a = e[t], b = e[t + 4];
        float2 d = make_float2(a.x - b.x, a.y - b.y);
        e[t] = make_float2(a.x + b.x, a.y + b.y);
        d = cmul(d, w1);
        if (t == 1)      d = make_float2(RSQ2 * (d.x + d.y), RSQ2 * (d.y - d.x));
        else if (t == 2) d = make_float2(d.y, -d.x);
        else if (t == 3) d = make_float2(RSQ2 * (d.y - d.x), -RSQ2 * (d.x + d.y));
        e[t + 4] = d;
    }
#pragma unroll
    for (int t0 = 0; t0 < 8; t0 += 4) {
#pragma unroll
        for (int t = 0; t < 2; ++t) {
            int i = t0 + t;
            float2 a = e[i], b = e[i + 2];
            float2 d = make_float2(a.x - b.x, a.y - b.y);
            e[i] = make_float2(a.x + b.x, a.y + b.y);
            d = cmul(d, w2);
            if (t == 1) d = make_float2(d.y, -d.x);
            e[i + 2] = d;
        }
    }
#pragma unroll
    for (int t = 0; t < 8; t += 2) {
        float2 a = e[t], b = e[t + 1];
        float2 d = make_float2(a.x - b.x, a.y - b.y);
        e[t] = make_float2(a.x + b.x, a.y + b.y);
        e[t + 1] = cmul(d, w3);
    }
#pragma unroll
    for (int t = 0; t < 8; ++t) buf[SW(i0 + t * s)] = e[t];
}

// C0 pass (unit twiddles) that KEEPS its outputs in e[] (Zt for the acc).
__device__ __forceinline__ void fwd_pass0_keep(float2* buf, int tid, float2* e) {
    const int i0 = tid << 3;
#pragma unroll
    for (int t = 0; t < 8; ++t) e[t] = buf[SW(i0 + t)];
#pragma unroll
    for (int t = 0; t < 4; ++t) {
        float2 a = e[t], b = e[t + 4];
        float2 d = make_float2(a.x - b.x, a.y - b.y);
        e[t] = make_float2(a.x + b.x, a.y + b.y);
        if (t == 1)      d = make_float2(RSQ2 * (d.x + d.y), RSQ2 * (d.y - d.x));
        else if (t == 2) d = make_float2(d.y, -d.x);
        else if (t == 3) d = make_float2(RSQ2 * (d.y - d.x), -RSQ2 * (d.x + d.y));
        e[t + 4] = d;
    }
#pragma unroll
    for (int t0 = 0; t0 < 8; t0 += 4) {
#pragma unroll
        for (int t = 0; t < 2; ++t) {
            int i = t0 + t;
            float2 a = e[i], b = e[i + 2];
            float2 d = make_float2(a.x - b.x, a.y - b.y);
            e[i] = make_float2(a.x + b.x, a.y + b.y);
            if (t == 1) d = make_float2(d.y, -d.x);
            e[i + 2] = d;
        }
    }
#pragma unroll
    for (int t = 0; t < 8; t += 2) {
        float2 a = e[t], b = e[t + 1];
        e[t]     = make_float2(a.x + b.x, a.y + b.y);
        e[t + 1] = make_float2(a.x - b.x, a.y - b.y);
    }
#pragma unroll
    for (int t = 0; t < 8; ++t) buf[SW(i0 + t)] = e[t];
}

// Inverse DIT radix-8 pass: stages (s, 2s, 4s), conjugated twiddles.
template<int C>
__device__ __forceinline__ void inv_pass(float2* buf, int tid) {
    const int s = 1 << C;
    const int q0 = tid & (s - 1);
    const int i0 = ((tid >> C) << (C + 3)) + q0;
    float2 e[8];
#pragma unroll
    for (int t = 0; t < 8; ++t) e[t] = buf[SW(i0 + t * s)];
    float2 v1 = g_W[q0 << (10 - C)]; v1.y = -v1.y;
    float2 v2 = cmul(v1, v1), v3 = cmul(v2, v2);
#pragma unroll
    for (int t = 0; t < 8; t += 2) {
        float2 b = cmul(e[t + 1], v3);
        float2 a = e[t];
        e[t]     = make_float2(a.x + b.x, a.y + b.y);
        e[t + 1] = make_float2(a.x - b.x, a.y - b.y);
    }
#pragma unroll
    for (int t0 = 0; t0 < 8; t0 += 4) {
#pragma unroll
        for (int t = 0; t < 2; ++t) {
            int i = t0 + t;
            float2 b = cmul(e[i + 2], v2);
            if (t == 1) b = make_float2(-b.y, b.x);
            float2 a = e[i];
            e[i]     = make_float2(a.x + b.x, a.y + b.y);
            e[i + 2] = make_float2(a.x - b.x, a.y - b.y);
        }
    }
#pragma unroll
    for (int t = 0; t < 4; ++t) {
        float2 b = cmul(e[t + 4], v1);
        if (t == 1)      b = make_float2(RSQ2 * (b.x - b.y), RSQ2 * (b.x + b.y));
        else if (t == 2) b = make_float2(-b.y, b.x);
        else if (t == 3) b = make_float2(-RSQ2 * (b.x + b.y), RSQ2 * (b.x - b.y));
        float2 a = e[t];
        e[t]     = make_float2(a.x + b.x, a.y + b.y);
        e[t + 4] = make_float2(a.x - b.x, a.y - b.y);
    }
#pragma unroll
    for (int t = 0; t < 8; ++t) buf[SW(i0 + t * s)] = e[t];
}

__device__ __forceinline__ void stage1_store(float2* buf, int u, float2 a, float2 b2) {
    float2 w = g_W[u];
    buf[SW(u)] = make_float2(a.x + b2.x, a.y + b2.y);
    buf[SW(u + HALF_TK)] = cmul(make_float2(a.x - b2.x, a.y - b2.y), w);
}

// FFT body (C9..C0, wave-chained tail) + accumulate into LDS accL.
// P loads hoisted above the C6/C3/C0 region; Q loaded at use.
template<bool FIRST>
__device__ __forceinline__ void fft_body_acc_lds(float2* buf, float2* accL, int tid,
                                                 const float2* __restrict__ P,
                                                 const float2* __restrict__ Q) {
    __syncthreads();
    fwd_pass<9>(buf, tid);
    __syncthreads();
    // --- hoisted P loads: latency hides under C6/C3/C0 (~2us of compute) ---
    float2 Pv[8];
#pragma unroll
    for (int c = 0; c < 8; ++c) Pv[c] = P[8 * tid + c];
    SCHED_FENCE();   // keep the loads up here (prevent sinking to the acc)
    fwd_pass<6>(buf, tid);
    WAVE_SYNC();
    fwd_pass<3>(buf, tid);
    WAVE_SYNC();
    float2 e0[8];
    fwd_pass0_keep(buf, tid, e0);   // Zt stays in regs; buf write feeds Zm
    __syncthreads();
    // accL[8*tid+c] is per-thread-exclusive -> RMW with no barrier.
#pragma unroll
    for (int c = 0; c < 8; ++c) {
        int r = 8 * tid + c;
        unsigned t = br13((unsigned)r);
        unsigned tm = (TK - t) & (TK - 1);
        int r2 = (int)br13(tm);
        float2 Zt = e0[c];
        float2 Zm = buf[SW(r2)];
        float2 Qv = Q[r];
        float2 a;
        if (FIRST) { a = make_float2(0.f, 0.f); }
        else       { a = accL[SW(r)]; }
        a.x += Zt.x * Pv[c].x - Zt.y * Pv[c].y + Zm.x * Qv.x + Zm.y * Qv.y;
        a.y += Zt.x * Pv[c].y + Zt.y * Pv[c].x + Zm.x * Qv.y - Zm.y * Qv.x;
        accL[SW(r)] = a;
    }
    __syncthreads();   // buf reads done before next j's load overwrites
}

__global__ __launch_bounds__(NT, 4)   // (1024,4): proven VGPR=64 allocator mode
void conv_fft_kernel(const float* __restrict__ x, float2* __restrict__ out) {
    __shared__ float2 buf[TK];     // 64 KB FFT workspace
    __shared__ float2 accL[TK];    // 64 KB accumulator (per-thread slots)
    const int tid = threadIdx.x;
    const int b = blockIdx.x;
    const float4* __restrict__ xrow4 =
        reinterpret_cast<const float4*>(x + (size_t)b * TFULL);

    // ---- j = 0: load even float4s, use .xy, stash .zw for j = 1 ----
    float2 s1a[4], s1b[4];
#pragma unroll
    for (int c4 = 0; c4 < 4; ++c4) {
        int u = c4 * NT + tid;
        float4 A = xrow4[2 * u];
        float4 B = xrow4[2 * (u + HALF_TK)];
        s1a[c4] = make_float2(A.z, A.w);
        s1b[c4] = make_float2(B.z, B.w);
        stage1_store(buf, u, make_float2(A.x, A.y), make_float2(B.x, B.y));
    }
    fft_body_acc_lds<true>(buf, accL, tid, g_P + 0 * TK, g_Q + 0 * TK);

    // ---- j = 1: stage-1 from register stash ----
#pragma unroll
    for (int c4 = 0; c4 < 4; ++c4) {
        int u = c4 * NT + tid;
        stage1_store(buf, u, s1a[c4], s1b[c4]);
    }
    fft_body_acc_lds<false>(buf, accL, tid, g_P + 1 * TK, g_Q + 1 * TK);

    // ---- j = 2: load odd float4s, use .xy, stash .zw for j = 3 ----
#pragma unroll
    for (int c4 = 0; c4 < 4; ++c4) {
        int u = c4 * NT + tid;
        float4 A = xrow4[2 * u + 1];
        float4 B = xrow4[2 * (u + HALF_TK) + 1];
        s1a[c4] = make_float2(A.z, A.w);
        s1b[c4] = make_float2(B.z, B.w);
        stage1_store(buf, u, make_float2(A.x, A.y), make_float2(B.x, B.y));
    }
    fft_body_acc_lds<false>(buf, accL, tid, g_P + 2 * TK, g_Q + 2 * TK);

    // ---- j = 3: stage-1 from register stash ----
#pragma unroll
    for (int c4 = 0; c4 < 4; ++c4) {
        int u = c4 * NT + tid;
        stage1_store(buf, u, s1a[c4], s1b[c4]);
    }
    fft_body_acc_lds<false>(buf, accL, tid, g_P + 3 * TK, g_Q + 3 * TK);

    // ---- inverse tail: read own acc slots, reg inverse C0, then C3..C9 ----
    {
        float2 acc[8], e[8];
#pragma unroll
        for (int c = 0; c < 8; ++c) acc[c] = accL[SW(8 * tid + c)];
        // stage h = 1
#pragma unroll
        for (int t = 0; t < 8; t += 2) {
            float2 a = acc[t], bb = acc[t + 1];
            e[t]     = make_float2(a.x + bb.x, a.y + bb.y);
            e[t + 1] = make_float2(a.x - bb.x, a.y - bb.y);
        }
        // stage h = 2 (twiddle (+i)^(t&1))
#pragma unroll
        for (int t0 = 0; t0 < 8; t0 += 4) {
            {
                float2 a = e[t0], bb = e[t0 + 2];
                e[t0]     = make_float2(a.x + bb.x, a.y + bb.y);
                e[t0 + 2] = make_float2(a.x - bb.x, a.y - bb.y);
            }
            {
                float2 a = e[t0 + 1], bb = e[t0 + 3];
                bb = make_float2(-bb.y, bb.x);
                e[t0 + 1] = make_float2(a.x + bb.x, a.y + bb.y);
                e[t0 + 3] = make_float2(a.x - bb.x, a.y - bb.y);
            }
        }
        // stage h = 4 (twiddle conj(u8)^t)
#pragma unroll
        for (int t = 0; t < 4; ++t) {
            float2 bb = e[t + 4];
            if (t == 1)      bb = make_float2(RSQ2 * (bb.x - bb.y), RSQ2 * (bb.x + bb.y));
            else if (t == 2) bb = make_float2(-bb.y, bb.x);
            else if (t == 3) bb = make_float2(-RSQ2 * (bb.x + bb.y), RSQ2 * (bb.x - bb.y));
            float2 a = e[t];
            e[t]     = make_float2(a.x + bb.x, a.y + bb.y);
            e[t + 4] = make_float2(a.x - bb.x, a.y - bb.y);
        }
#pragma unroll
        for (int t = 0; t < 8; ++t) buf[SW(8 * tid + t)] = e[t];
    }
    WAVE_SYNC();
    // C0 -> C3 -> C6 same-wave; barrier before the cross-wave C9
    inv_pass<3>(buf, tid);
    WAVE_SYNC();
    inv_pass<6>(buf, tid);
    __syncthreads();
    inv_pass<9>(buf, tid);
    __syncthreads();
    // final DIT stage (h = 4096) fused with global store
    float2* __restrict__ orow = out + (size_t)b * TK;
#pragma unroll
    for (int c4 = 0; c4 < 4; ++c4) {
        int u = c4 * NT + tid;
        float2 a = buf[SW(u)];
        float2 w = g_W[u]; w.y = -w.y;
        float2 bb = cmul(buf[SW(u + HALF_TK)], w);
        orow[u]           = make_float2(a.x + bb.x, a.y + bb.y);
        orow[u + HALF_TK] = make_float2(a.x - bb.x, a.y - bb.y);
    }
}

extern "C" void kernel_launch(void* const* d_in, const int* in_sizes, int n_in,
                              void* d_out, int out_size, void* d_ws, size_t ws_size,
                              hipStream_t stream) {
    const float* x    = (const float*)d_in[0];
    const float* filt = (const float*)d_in[1];
    const int T = in_sizes[1];          // 65536
    const int B = in_sizes[0] / T;      // 256 rows
    (void)n_in; (void)d_ws; (void)ws_size; (void)out_size; (void)T;

    build_tables_kernel<<<TK / 256, 256, 0, stream>>>(filt);
    conv_fft_kernel<<<B, NT, 0, stream>>>(x, (float2*)d_out);
}